// Round 15
// baseline (316.688 us; speedup 1.0000x reference)
//
#include <hip/hip_runtime.h>
#include <hip/hip_bf16.h>
#include <stdint.h>

#define VOCAB 50000
#define EMB   300
#define EMBP  320   // K padded to multiple of 64
#define HID   128
#define NGATE 512   // 4*HID
#define BATCH 1024
#define SEQ   200
#define ROWS  4     // batch rows per k_lstm block (256 blocks)
#define L2E   1.4426950408889634f

typedef __attribute__((ext_vector_type(8))) short short8;
typedef __attribute__((ext_vector_type(4))) float f32x4;

#define AS1 __attribute__((address_space(1)))
#define AS3 __attribute__((address_space(3)))

static __device__ __forceinline__ void gload_lds16(const void* g, void* s) {
  __builtin_amdgcn_global_load_lds((const AS1 uint32_t*)g, (AS3 uint32_t*)s, 16, 0, 0);
}

static __device__ __forceinline__ unsigned short f2bf(float f) {
  union { float f; unsigned u; } v; v.f = f;
  unsigned r = v.u + 0x7fffu + ((v.u >> 16) & 1u);
  return (unsigned short)(r >> 16);
}
static __device__ __forceinline__ float blo2f(unsigned u) {
  union { unsigned u; float f; } v; v.u = u << 16; return v.f;
}
static __device__ __forceinline__ float bhi2f(unsigned u) {
  union { unsigned u; float f; } v; v.u = u & 0xffff0000u; return v.f;
}
static __device__ __forceinline__ float sigmf(float x) {
  return __fdividef(1.0f, 1.0f + __expf(-x));
}
// z pre-scaled by log2(e): sigmoid(a) = 1/(1+2^-z)
static __device__ __forceinline__ float sig2(float z) {
  return __builtin_amdgcn_rcpf(1.0f + __builtin_amdgcn_exp2f(-z));
}

// ---------------- prep: f32 -> bf16 (K-pad; optional perm / gate scale) ----
// NT loads on the f32 source (stream-once) keep L3 free for the bf16 tables.
__global__ void k_cvt_pad(const float* __restrict__ src, unsigned short* __restrict__ dst,
                          int rows, int sc, int dc, int perm, int smode) {
  int idx = blockIdx.x * blockDim.x + threadIdx.x;
  int cpr = dc >> 3;
  if (idx >= rows * cpr) return;
  int row = idx / cpr, k0 = (idx - row * cpr) * 8;
  float s = 1.0f;
  if (smode) s = ((row >> 7) == 2) ? (2.0f * L2E) : L2E;
  uint4 pack;
  unsigned short* v = (unsigned short*)&pack;
#pragma unroll
  for (int j = 0; j < 8; j++) {
    int k = k0 + j;
    v[j] = (k < sc) ? f2bf(__builtin_nontemporal_load(src + (long)row * sc + k) * s)
                    : (unsigned short)0;
  }
  int drow = perm ? ((row & 127) * 4 + (row >> 7)) : row;
  *(uint4*)(dst + (long)drow * dc + k0) = pack;
}

// permuted+scaled bias: o[hid*4+g] = (a[g*128+hid]+b[...]) * s_g
__global__ void k_bias(const float* __restrict__ a, const float* __restrict__ b,
                       float* __restrict__ o) {
  int i = blockIdx.x * blockDim.x + threadIdx.x;
  if (i < NGATE) {
    int g = i >> 7, hid = i & 127;
    float s = (g == 2) ? (2.0f * L2E) : L2E;
    o[hid * 4 + g] = (a[i] + b[i]) * s;
  }
}

// ---------------- kernel 1: gathered GEMM  xg = emb[x] @ w_ih_perm^T + bias
// R14 structure + NT stores for xg: the 205MB xg stream no longer allocates
// in L2/L3, so the emb bf16 table stays L3-resident and the A-gather (the
// staging-BW term this kernel is bound on) hits L3 instead of HBM.
__global__ __launch_bounds__(512, 4) void k_xg_gemm(
    const int* __restrict__ x, const unsigned short* __restrict__ embb,
    const unsigned short* __restrict__ wihb, const float* __restrict__ biasp,
    unsigned short* __restrict__ xg) {
  __shared__ __align__(16) unsigned short Al[2][128 * 64];   // 32 KB
  __shared__ __align__(16) unsigned short Bl[2][128 * 64];   // 32 KB
  const int tid = threadIdx.x;
  const int lane = tid & 63;
  // XCD co-location: bid = q*8 + xcd ; tile_m = xcd*200 + q/4 ; tile_n = q%4
  const int bid = blockIdx.x;
  const int xcd = bid & 7;
  const int q = bid >> 3;                   // 0..799
  const int tile_m = xcd * 200 + (q >> 2);  // 0..1599
  const int tile_n = q & 3;
  const int t_idx = tile_m >> 3;            // 1024 % 128 == 0 -> tile same t
  const int b0 = (tile_m & 7) * 128;
  const int n0 = tile_n * 128;

  // staging: chunk c = tid + i*512 (i<2); row = c>>3, phys slot p = c&7
  // sigma = p ^ (row&7) ; row&7 identical for both i (64 % 8 == 0)
  const int r0 = tid >> 3;                  // 0..63
  const int sg = (tid & 7) ^ (r0 & 7);
  const unsigned short* asrc[2];
  const unsigned short* bsrc[2];
#pragma unroll
  for (int i = 0; i < 2; i++) {
    const int r = r0 + i * 64;
    const long ridx = x[(b0 + r) * SEQ + t_idx];
    asrc[i] = embb + ridx * EMBP + sg * 8;
    bsrc[i] = wihb + (long)(n0 + r) * EMBP + sg * 8;
  }

  // wave mapping: 8 waves = 4 wrow (32 M-rows) x 2 wcol (64 N-cols)
  const int wid = tid >> 6;
  const int wrow = wid >> 1, wcol = wid & 1;
  const int l15 = lane & 15, lgrp = lane >> 4;
  const int swz = (l15 & 7) << 4;

  f32x4 acc[2][4];
#pragma unroll
  for (int mt = 0; mt < 2; mt++)
#pragma unroll
    for (int nt = 0; nt < 4; nt++) acc[mt][nt] = (f32x4){0.f, 0.f, 0.f, 0.f};

#define STAGE(KS, BUF)                                                         \
  {                                                                            \
    _Pragma("unroll") for (int i = 0; i < 2; i++) {                            \
      gload_lds16(asrc[i] + (KS) * 64, (char*)Al + (BUF) * 16384 + tid * 16 + i * 8192); \
      gload_lds16(bsrc[i] + (KS) * 64, (char*)Bl + (BUF) * 16384 + tid * 16 + i * 8192); \
    }                                                                          \
  }

#define COMPUTE(BUF)                                                           \
  {                                                                            \
    const char* Ar = (const char*)Al + (BUF) * 16384 + (wrow * 32) * 128;      \
    const char* Br = (const char*)Bl + (BUF) * 16384 + (wcol * 64) * 128;      \
    _Pragma("unroll") for (int kt = 0; kt < 2; kt++) {                         \
      short8 af[2], bf[4];                                                     \
      _Pragma("unroll") for (int mt = 0; mt < 2; mt++)                         \
        af[mt] = *(const short8*)(Ar + (mt * 16 + l15) * 128 + ((kt * 64 + lgrp * 16) ^ swz)); \
      _Pragma("unroll") for (int nt = 0; nt < 4; nt++)                         \
        bf[nt] = *(const short8*)(Br + (nt * 16 + l15) * 128 + ((kt * 64 + lgrp * 16) ^ swz)); \
      __builtin_amdgcn_s_setprio(1);                                           \
      _Pragma("unroll") for (int mt = 0; mt < 2; mt++)                         \
        _Pragma("unroll") for (int nt = 0; nt < 4; nt++)                       \
          acc[mt][nt] = __builtin_amdgcn_mfma_f32_16x16x32_bf16(af[mt], bf[nt], acc[mt][nt], 0, 0, 0); \
      __builtin_amdgcn_s_setprio(0);                                           \
    }                                                                          \
  }

  STAGE(0, 0);
  __syncthreads();
  STAGE(1, 1); COMPUTE(0); __syncthreads();
  STAGE(2, 0); COMPUTE(1); __syncthreads();
  STAGE(3, 1); COMPUTE(0); __syncthreads();
  STAGE(4, 0); COMPUTE(1); __syncthreads();
  COMPUTE(0);
#undef STAGE
#undef COMPUTE

  const int m_base = tile_m * 128 + wrow * 32;
  const int colg = n0 + wcol * 64 + l15;
  const int rsub = lgrp * 4;
  float bv[4];
#pragma unroll
  for (int nt = 0; nt < 4; nt++) bv[nt] = biasp[colg + nt * 16];
#pragma unroll
  for (int mt = 0; mt < 2; mt++)
#pragma unroll
    for (int nt = 0; nt < 4; nt++)
#pragma unroll
      for (int j = 0; j < 4; j++) {
        const long m = m_base + mt * 16 + rsub + j;
        __builtin_nontemporal_store(f2bf(acc[mt][nt][j] + bv[nt]),
                                    xg + m * NGATE + colg + nt * 16);
      }
}

// ---------------- kernel 2: sequential LSTM (R14 champion, verbatim) -------
__global__ __launch_bounds__(512, 2) void k_lstm(
    const unsigned short* __restrict__ xg, const unsigned short* __restrict__ whhp,
    float* __restrict__ hfin) {
  __shared__ __align__(16) unsigned short h_lds[2 * 4 * 128];  // 2KB dbuf, XOR-swizzled
  __shared__ __align__(16) float scratch[8 * 256];             // 8KB: 1KB per wave
  const int tid = threadIdx.x;
  const int lane = tid & 63;
  const int wid = tid >> 6;        // hidden block (16 hids)
  const int b0 = blockIdx.x * ROWS;
  const int l15 = lane & 15;
  const int lgrp = lane >> 4;      // 0..3
  const int hid = wid * 16 + l15;  // updater's hid

  // A-operand: permuted w_hh rows n' = wid*64 + nt*16 + l15, k = kt*32+lgrp*8
  short8 wfr[4][4];
#pragma unroll
  for (int nt = 0; nt < 4; nt++)
#pragma unroll
    for (int kt = 0; kt < 4; kt++)
      wfr[nt][kt] = *(const short8*)(whhp + (long)(wid * 64 + nt * 16 + l15) * HID + kt * 32 + lgrp * 8);

  float c_r = 0.0f, h_r = 0.0f;    // element (row=lgrp, hid)

  ((unsigned*)h_lds)[tid] = 0;     // 512 x 4B = 2KB (both parities)
  __syncthreads();

  // B-frag (h^T): lane l15 -> batch row l15&3 (rows 4-15 dup -> garbage cols)
  const int ar = l15 & 3;
  int rdoff[4];
#pragma unroll
  for (int kt = 0; kt < 4; kt++)
    rdoff[kt] = ar * 256 + ((kt * 64 + lgrp * 16) ^ (ar << 5));
  const int hwoff = lgrp * 256 + ((2 * hid) ^ (lgrp << 5));
  const char* lb = (const char*)h_lds;

  // wave-private scratch: float addr (row r)*64 + ((hidloc*4) ^ (r*4))
  float* sw = scratch + wid * 256;
  int swr[4];                       // write: r=l15 (<4), hidloc = nt*4+lgrp
#pragma unroll
  for (int nt = 0; nt < 4; nt++)
    swr[nt] = l15 * 64 + (((nt * 4 + lgrp) * 4) ^ (l15 * 4));
  const int srd = lgrp * 64 + ((l15 * 4) ^ (lgrp * 4));  // read: r=lgrp, hidloc=l15

  // xg: elem ((t*BATCH + row)*HID + hid)*4 + gate ; this lane: row=lgrp
  const unsigned short* xbase = xg + ((long)(b0 + lgrp) * HID + hid) * 4;
  const long TSTEP = (long)BATCH * HID * 4;
  uint2 xA = *(const uint2*)xbase;
  uint2 xB = *(const uint2*)(xbase + TSTEP);
  const unsigned short* xnext = xbase + 2 * TSTEP;

#define STEP_BODY(XS, RB, WB, T)                                               \
  {                                                                            \
    const float xf0 = blo2f(XS.x), xf1 = bhi2f(XS.x);                          \
    const float xf2 = blo2f(XS.y), xf3 = bhi2f(XS.y);                          \
    if ((T) + 2 < SEQ) XS = *(const uint2*)xnext;                              \
    short8 hf[4];                                                              \
    _Pragma("unroll") for (int kt = 0; kt < 4; kt++)                           \
      hf[kt] = *(const short8*)(lb + (RB) + rdoff[kt]);                        \
    f32x4 acc[4];                                                              \
    _Pragma("unroll") for (int nt = 0; nt < 4; nt++)                           \
      acc[nt] = (f32x4){0.f, 0.f, 0.f, 0.f};                                   \
    __builtin_amdgcn_s_setprio(1);                                             \
    _Pragma("unroll") for (int kt = 0; kt < 4; kt++)                           \
      _Pragma("unroll") for (int nt = 0; nt < 4; nt++)                         \
        acc[nt] = __builtin_amdgcn_mfma_f32_16x16x32_bf16(wfr[nt][kt], hf[kt], \
                                                          acc[nt], 0, 0, 0);   \
    __builtin_amdgcn_s_setprio(0);                                             \
    if (l15 < 4) {                                                             \
      _Pragma("unroll") for (int nt = 0; nt < 4; nt++)                         \
        *(f32x4*)(sw + swr[nt]) = acc[nt];                                     \
    }                                                                          \
    __builtin_amdgcn_sched_barrier(0);                                         \
    const f32x4 g4 = *(const f32x4*)(sw + srd);                                \
    const float zi = g4[0] + xf0;                                              \
    const float zf = g4[1] + xf1;                                              \
    const float zg = g4[2] + xf2;                                              \
    const float zo = g4[3] + xf3;                                              \
    const float iv = sig2(zi);                                                 \
    const float fv = sig2(zf);                                                 \
    const float gv = 2.0f * sig2(zg) - 1.0f;                                   \
    const float ov = sig2(zo);                                                 \
    c_r = fv * c_r + iv * gv;                                                  \
    const float tc = 2.0f * sig2(c_r * (2.0f * L2E)) - 1.0f;                   \
    h_r = ov * tc;                                                             \
    *(unsigned short*)((char*)h_lds + (WB) + hwoff) = f2bf(h_r);               \
    asm volatile("s_waitcnt lgkmcnt(0)" ::: "memory");                         \
    __builtin_amdgcn_s_barrier();                                              \
    __builtin_amdgcn_sched_barrier(0);                                         \
  }

  for (int t = 0; t < SEQ; t += 2) {
    STEP_BODY(xA, 0, 1024, t);
    xnext += TSTEP;
    STEP_BODY(xB, 1024, 0, t + 1);
    xnext += TSTEP;
  }
#undef STEP_BODY

  hfin[(b0 + lgrp) * HID + hid] = h_r;
}

// ---------------- kernel 3: FC head, one wave per batch row ----------------
__global__ void k_head(const float* __restrict__ hfin,
                       const float* __restrict__ fc1w, const float* __restrict__ fc1b,
                       const float* __restrict__ fc2w, const float* __restrict__ fc2b,
                       float* __restrict__ out) {
  const int tid = threadIdx.x;
  const int lane = tid & 63;
  const int wid = tid >> 6;
  const int row = blockIdx.x * 4 + wid;
  const float* h = hfin + row * HID;
  const float* w = fc1w + lane * HID;
  float acc = 0.0f;
#pragma unroll
  for (int k = 0; k < HID; k += 4) {
    const f32x4 hv = *(const f32x4*)(h + k);
    const f32x4 wv = *(const f32x4*)(w + k);
    acc += hv[0] * wv[0] + hv[1] * wv[1] + hv[2] * wv[2] + hv[3] * wv[3];
  }
  const float h1 = fmaxf(acc + fc1b[lane], 0.0f);
  float v = h1 * fc2w[lane];
#pragma unroll
  for (int off = 32; off > 0; off >>= 1) v += __shfl_down(v, off, 64);
  if (lane == 0) out[row] = sigmf(v + fc2b[0]);
}

// ---------------------------------------------------------------------------
extern "C" void kernel_launch(void* const* d_in, const int* in_sizes, int n_in,
                              void* d_out, int out_size, void* d_ws, size_t ws_size,
                              hipStream_t stream) {
  const int*   x    = (const int*)d_in[0];
  const float* emb  = (const float*)d_in[1];
  const float* w_ih = (const float*)d_in[2];
  const float* w_hh = (const float*)d_in[3];
  const float* b_ih = (const float*)d_in[4];
  const float* b_hh = (const float*)d_in[5];
  const float* fc1w = (const float*)d_in[6];
  const float* fc1b = (const float*)d_in[7];
  const float* fc2w = (const float*)d_in[8];
  const float* fc2b = (const float*)d_in[9];
  float* out = (float*)d_out;
  char* ws = (char*)d_ws;

  unsigned short* embb = (unsigned short*)(ws + 0);            // 32,000,000
  unsigned short* wihb = (unsigned short*)(ws + 32000000);     //    327,680
  unsigned short* whhp = (unsigned short*)(ws + 32327680);     //    131,072 (PERMUTED w_hh)
  float*          biasp= (float*)(ws + 32458752);              //      2,048
  float*          hfinp= (float*)(ws + 32460800);              //    524,288
  unsigned short* xgb  = (unsigned short*)(ws + 32985088);     // 209,715,200

  k_cvt_pad<<<dim3((VOCAB * (EMBP / 8) + 255) / 256), dim3(256), 0, stream>>>(emb, embb, VOCAB, EMB, EMBP, 0, 0);
  k_cvt_pad<<<dim3((NGATE * (EMBP / 8) + 255) / 256), dim3(256), 0, stream>>>(w_ih, wihb, NGATE, EMB, EMBP, 1, 1);
  k_cvt_pad<<<dim3((NGATE * (HID / 8) + 255) / 256), dim3(256), 0, stream>>>(w_hh, whhp, NGATE, HID, HID, 1, 1);
  k_bias<<<dim3(2), dim3(256), 0, stream>>>(b_ih, b_hh, biasp);
  k_xg_gemm<<<dim3(1600 * 4), dim3(512), 0, stream>>>(x, embb, wihb, biasp, xgb);
  k_lstm<<<dim3(BATCH / ROWS), dim3(512), 0, stream>>>(xgb, whhp, hfinp);
  k_head<<<dim3(256), dim3(256), 0, stream>>>(hfinp, fc1w, fc1b, fc2w, fc2b, out);
  (void)in_sizes; (void)n_in; (void)out_size; (void)ws_size;
}

// Round 16
// 264.605 us; speedup vs baseline: 1.1968x; 1.1968x over previous
//
#include <hip/hip_runtime.h>
#include <hip/hip_bf16.h>
#include <stdint.h>

#define VOCAB 50000
#define EMB   300
#define EMBP  320   // K padded to multiple of 64
#define HID   128
#define NGATE 512   // 4*HID
#define BATCH 1024
#define SEQ   200
#define ROWS  4     // batch rows per k_lstm block (256 blocks)
#define L2E   1.4426950408889634f

typedef __attribute__((ext_vector_type(8))) short short8;
typedef __attribute__((ext_vector_type(4))) float f32x4;

#define AS1 __attribute__((address_space(1)))
#define AS3 __attribute__((address_space(3)))

static __device__ __forceinline__ void gload_lds16(const void* g, void* s) {
  __builtin_amdgcn_global_load_lds((const AS1 uint32_t*)g, (AS3 uint32_t*)s, 16, 0, 0);
}

static __device__ __forceinline__ unsigned short f2bf(float f) {
  union { float f; unsigned u; } v; v.f = f;
  unsigned r = v.u + 0x7fffu + ((v.u >> 16) & 1u);
  return (unsigned short)(r >> 16);
}
static __device__ __forceinline__ float blo2f(unsigned u) {
  union { unsigned u; float f; } v; v.u = u << 16; return v.f;
}
static __device__ __forceinline__ float bhi2f(unsigned u) {
  union { unsigned u; float f; } v; v.u = u & 0xffff0000u; return v.f;
}
static __device__ __forceinline__ float sigmf(float x) {
  return __fdividef(1.0f, 1.0f + __expf(-x));
}
// z pre-scaled by log2(e): sigmoid(a) = 1/(1+2^-z)
static __device__ __forceinline__ float sig2(float z) {
  return __builtin_amdgcn_rcpf(1.0f + __builtin_amdgcn_exp2f(-z));
}

// ---------------- FUSED prep: all f32->bf16 conversions + bias in ONE launch
// ranges: [0,EMBN) emb cvt | [..,+WIHN) w_ih perm+scale | [..,+WHHN) w_hh
// perm+scale | [..,+NGATE) bias. Math identical to the R14 k_cvt_pad/k_bias.
__global__ __launch_bounds__(256) void k_prep(
    const float* __restrict__ emb, const float* __restrict__ w_ih,
    const float* __restrict__ w_hh, const float* __restrict__ b_ih,
    const float* __restrict__ b_hh, unsigned short* __restrict__ embb,
    unsigned short* __restrict__ wihb, unsigned short* __restrict__ whhp,
    float* __restrict__ biasp) {
  const long EMBN = (long)VOCAB * (EMBP / 8);   // 2,000,000
  const long WIHN = NGATE * (EMBP / 8);         //    20,480
  const long WHHN = NGATE * (HID / 8);          //     8,192
  long idx = (long)blockIdx.x * blockDim.x + threadIdx.x;

  if (idx < EMBN) {
    const int row = (int)(idx / (EMBP / 8));
    const int k0 = (int)(idx - (long)row * (EMBP / 8)) * 8;
    uint4 pack;
    unsigned short* v = (unsigned short*)&pack;
#pragma unroll
    for (int j = 0; j < 8; j++) {
      const int k = k0 + j;
      v[j] = (k < EMB) ? f2bf(emb[(long)row * EMB + k]) : (unsigned short)0;
    }
    *(uint4*)(embb + (long)row * EMBP + k0) = pack;
    return;
  }
  idx -= EMBN;
  if (idx < WIHN) {
    const int row = (int)(idx / (EMBP / 8));
    const int k0 = (int)(idx - (long)row * (EMBP / 8)) * 8;
    const float s = ((row >> 7) == 2) ? (2.0f * L2E) : L2E;
    uint4 pack;
    unsigned short* v = (unsigned short*)&pack;
#pragma unroll
    for (int j = 0; j < 8; j++) {
      const int k = k0 + j;
      v[j] = (k < EMB) ? f2bf(w_ih[(long)row * EMB + k] * s) : (unsigned short)0;
    }
    const int drow = (row & 127) * 4 + (row >> 7);
    *(uint4*)(wihb + (long)drow * EMBP + k0) = pack;
    return;
  }
  idx -= WIHN;
  if (idx < WHHN) {
    const int row = (int)(idx / (HID / 8));
    const int k0 = (int)(idx - (long)row * (HID / 8)) * 8;
    const float s = ((row >> 7) == 2) ? (2.0f * L2E) : L2E;
    uint4 pack;
    unsigned short* v = (unsigned short*)&pack;
#pragma unroll
    for (int j = 0; j < 8; j++)
      v[j] = f2bf(w_hh[(long)row * HID + k0 + j] * s);
    const int drow = (row & 127) * 4 + (row >> 7);
    *(uint4*)(whhp + (long)drow * HID + k0) = pack;
    return;
  }
  idx -= WHHN;
  if (idx < NGATE) {
    const int g = (int)(idx >> 7), hid = (int)(idx & 127);
    const float s = (g == 2) ? (2.0f * L2E) : L2E;
    biasp[hid * 4 + g] = (b_ih[idx] + b_hh[idx]) * s;
  }
}

// ---------------- kernel 1: gathered GEMM  xg = emb[x] @ w_ih_perm^T + bias
// (R14 champion verbatim: 128x128 tile, 2-phase dbuf, XCD co-location,
// 64KB LDS, 8 waves / 512 thr, 2 blocks/CU, T5 setprio around MFMA)
__global__ __launch_bounds__(512, 4) void k_xg_gemm(
    const int* __restrict__ x, const unsigned short* __restrict__ embb,
    const unsigned short* __restrict__ wihb, const float* __restrict__ biasp,
    unsigned short* __restrict__ xg) {
  __shared__ __align__(16) unsigned short Al[2][128 * 64];   // 32 KB
  __shared__ __align__(16) unsigned short Bl[2][128 * 64];   // 32 KB
  const int tid = threadIdx.x;
  const int lane = tid & 63;
  // XCD co-location: bid = q*8 + xcd ; tile_m = xcd*200 + q/4 ; tile_n = q%4
  const int bid = blockIdx.x;
  const int xcd = bid & 7;
  const int q = bid >> 3;                   // 0..799
  const int tile_m = xcd * 200 + (q >> 2);  // 0..1599
  const int tile_n = q & 3;
  const int t_idx = tile_m >> 3;            // 1024 % 128 == 0 -> tile same t
  const int b0 = (tile_m & 7) * 128;
  const int n0 = tile_n * 128;

  // staging: chunk c = tid + i*512 (i<2); row = c>>3, phys slot p = c&7
  // sigma = p ^ (row&7) ; row&7 identical for both i (64 % 8 == 0)
  const int r0 = tid >> 3;                  // 0..63
  const int sg = (tid & 7) ^ (r0 & 7);
  const unsigned short* asrc[2];
  const unsigned short* bsrc[2];
#pragma unroll
  for (int i = 0; i < 2; i++) {
    const int r = r0 + i * 64;
    const long ridx = x[(b0 + r) * SEQ + t_idx];
    asrc[i] = embb + ridx * EMBP + sg * 8;
    bsrc[i] = wihb + (long)(n0 + r) * EMBP + sg * 8;
  }

  // wave mapping: 8 waves = 4 wrow (32 M-rows) x 2 wcol (64 N-cols)
  const int wid = tid >> 6;
  const int wrow = wid >> 1, wcol = wid & 1;
  const int l15 = lane & 15, lgrp = lane >> 4;
  const int swz = (l15 & 7) << 4;

  f32x4 acc[2][4];
#pragma unroll
  for (int mt = 0; mt < 2; mt++)
#pragma unroll
    for (int nt = 0; nt < 4; nt++) acc[mt][nt] = (f32x4){0.f, 0.f, 0.f, 0.f};

#define STAGE(KS, BUF)                                                         \
  {                                                                            \
    _Pragma("unroll") for (int i = 0; i < 2; i++) {                            \
      gload_lds16(asrc[i] + (KS) * 64, (char*)Al + (BUF) * 16384 + tid * 16 + i * 8192); \
      gload_lds16(bsrc[i] + (KS) * 64, (char*)Bl + (BUF) * 16384 + tid * 16 + i * 8192); \
    }                                                                          \
  }

#define COMPUTE(BUF)                                                           \
  {                                                                            \
    const char* Ar = (const char*)Al + (BUF) * 16384 + (wrow * 32) * 128;      \
    const char* Br = (const char*)Bl + (BUF) * 16384 + (wcol * 64) * 128;      \
    _Pragma("unroll") for (int kt = 0; kt < 2; kt++) {                         \
      short8 af[2], bf[4];                                                     \
      _Pragma("unroll") for (int mt = 0; mt < 2; mt++)                         \
        af[mt] = *(const short8*)(Ar + (mt * 16 + l15) * 128 + ((kt * 64 + lgrp * 16) ^ swz)); \
      _Pragma("unroll") for (int nt = 0; nt < 4; nt++)                         \
        bf[nt] = *(const short8*)(Br + (nt * 16 + l15) * 128 + ((kt * 64 + lgrp * 16) ^ swz)); \
      __builtin_amdgcn_s_setprio(1);                                           \
      _Pragma("unroll") for (int mt = 0; mt < 2; mt++)                         \
        _Pragma("unroll") for (int nt = 0; nt < 4; nt++)                       \
          acc[mt][nt] = __builtin_amdgcn_mfma_f32_16x16x32_bf16(af[mt], bf[nt], acc[mt][nt], 0, 0, 0); \
      __builtin_amdgcn_s_setprio(0);                                           \
    }                                                                          \
  }

  STAGE(0, 0);
  __syncthreads();
  STAGE(1, 1); COMPUTE(0); __syncthreads();
  STAGE(2, 0); COMPUTE(1); __syncthreads();
  STAGE(3, 1); COMPUTE(0); __syncthreads();
  STAGE(4, 0); COMPUTE(1); __syncthreads();
  COMPUTE(0);
#undef STAGE
#undef COMPUTE

  const int m_base = tile_m * 128 + wrow * 32;
  const int colg = n0 + wcol * 64 + l15;
  const int rsub = lgrp * 4;
  float bv[4];
#pragma unroll
  for (int nt = 0; nt < 4; nt++) bv[nt] = biasp[colg + nt * 16];
#pragma unroll
  for (int mt = 0; mt < 2; mt++)
#pragma unroll
    for (int nt = 0; nt < 4; nt++)
#pragma unroll
      for (int j = 0; j < 4; j++) {
        const long m = m_base + mt * 16 + rsub + j;
        xg[m * NGATE + colg + nt * 16] = f2bf(acc[mt][nt][j] + bv[nt]);
      }
}

// ---------------- kernel 2: sequential LSTM (R14 champion, verbatim) -------
__global__ __launch_bounds__(512, 2) void k_lstm(
    const unsigned short* __restrict__ xg, const unsigned short* __restrict__ whhp,
    float* __restrict__ hfin) {
  __shared__ __align__(16) unsigned short h_lds[2 * 4 * 128];  // 2KB dbuf, XOR-swizzled
  __shared__ __align__(16) float scratch[8 * 256];             // 8KB: 1KB per wave
  const int tid = threadIdx.x;
  const int lane = tid & 63;
  const int wid = tid >> 6;        // hidden block (16 hids)
  const int b0 = blockIdx.x * ROWS;
  const int l15 = lane & 15;
  const int lgrp = lane >> 4;      // 0..3
  const int hid = wid * 16 + l15;  // updater's hid

  // A-operand: permuted w_hh rows n' = wid*64 + nt*16 + l15, k = kt*32+lgrp*8
  short8 wfr[4][4];
#pragma unroll
  for (int nt = 0; nt < 4; nt++)
#pragma unroll
    for (int kt = 0; kt < 4; kt++)
      wfr[nt][kt] = *(const short8*)(whhp + (long)(wid * 64 + nt * 16 + l15) * HID + kt * 32 + lgrp * 8);

  float c_r = 0.0f, h_r = 0.0f;    // element (row=lgrp, hid)

  ((unsigned*)h_lds)[tid] = 0;     // 512 x 4B = 2KB (both parities)
  __syncthreads();

  // B-frag (h^T): lane l15 -> batch row l15&3 (rows 4-15 dup -> garbage cols)
  const int ar = l15 & 3;
  int rdoff[4];
#pragma unroll
  for (int kt = 0; kt < 4; kt++)
    rdoff[kt] = ar * 256 + ((kt * 64 + lgrp * 16) ^ (ar << 5));
  const int hwoff = lgrp * 256 + ((2 * hid) ^ (lgrp << 5));
  const char* lb = (const char*)h_lds;

  // wave-private scratch: float addr (row r)*64 + ((hidloc*4) ^ (r*4))
  float* sw = scratch + wid * 256;
  int swr[4];                       // write: r=l15 (<4), hidloc = nt*4+lgrp
#pragma unroll
  for (int nt = 0; nt < 4; nt++)
    swr[nt] = l15 * 64 + (((nt * 4 + lgrp) * 4) ^ (l15 * 4));
  const int srd = lgrp * 64 + ((l15 * 4) ^ (lgrp * 4));  // read: r=lgrp, hidloc=l15

  // xg: elem ((t*BATCH + row)*HID + hid)*4 + gate ; this lane: row=lgrp
  const unsigned short* xbase = xg + ((long)(b0 + lgrp) * HID + hid) * 4;
  const long TSTEP = (long)BATCH * HID * 4;
  uint2 xA = *(const uint2*)xbase;
  uint2 xB = *(const uint2*)(xbase + TSTEP);
  const unsigned short* xnext = xbase + 2 * TSTEP;

#define STEP_BODY(XS, RB, WB, T)                                               \
  {                                                                            \
    const float xf0 = blo2f(XS.x), xf1 = bhi2f(XS.x);                          \
    const float xf2 = blo2f(XS.y), xf3 = bhi2f(XS.y);                          \
    if ((T) + 2 < SEQ) XS = *(const uint2*)xnext;                              \
    short8 hf[4];                                                              \
    _Pragma("unroll") for (int kt = 0; kt < 4; kt++)                           \
      hf[kt] = *(const short8*)(lb + (RB) + rdoff[kt]);                        \
    f32x4 acc[4];                                                              \
    _Pragma("unroll") for (int nt = 0; nt < 4; nt++)                           \
      acc[nt] = (f32x4){0.f, 0.f, 0.f, 0.f};                                   \
    __builtin_amdgcn_s_setprio(1);                                             \
    _Pragma("unroll") for (int kt = 0; kt < 4; kt++)                           \
      _Pragma("unroll") for (int nt = 0; nt < 4; nt++)                         \
        acc[nt] = __builtin_amdgcn_mfma_f32_16x16x32_bf16(wfr[nt][kt], hf[kt], \
                                                          acc[nt], 0, 0, 0);   \
    __builtin_amdgcn_s_setprio(0);                                             \
    if (l15 < 4) {                                                             \
      _Pragma("unroll") for (int nt = 0; nt < 4; nt++)                         \
        *(f32x4*)(sw + swr[nt]) = acc[nt];                                     \
    }                                                                          \
    __builtin_amdgcn_sched_barrier(0);                                         \
    const f32x4 g4 = *(const f32x4*)(sw + srd);                                \
    const float zi = g4[0] + xf0;                                              \
    const float zf = g4[1] + xf1;                                              \
    const float zg = g4[2] + xf2;                                              \
    const float zo = g4[3] + xf3;                                              \
    const float iv = sig2(zi);                                                 \
    const float fv = sig2(zf);                                                 \
    const float gv = 2.0f * sig2(zg) - 1.0f;                                   \
    const float ov = sig2(zo);                                                 \
    c_r = fv * c_r + iv * gv;                                                  \
    const float tc = 2.0f * sig2(c_r * (2.0f * L2E)) - 1.0f;                   \
    h_r = ov * tc;                                                             \
    *(unsigned short*)((char*)h_lds + (WB) + hwoff) = f2bf(h_r);               \
    asm volatile("s_waitcnt lgkmcnt(0)" ::: "memory");                         \
    __builtin_amdgcn_s_barrier();                                              \
    __builtin_amdgcn_sched_barrier(0);                                         \
  }

  for (int t = 0; t < SEQ; t += 2) {
    STEP_BODY(xA, 0, 1024, t);
    xnext += TSTEP;
    STEP_BODY(xB, 1024, 0, t + 1);
    xnext += TSTEP;
  }
#undef STEP_BODY

  hfin[(b0 + lgrp) * HID + hid] = h_r;
}

// ---------------- kernel 3: FC head, one wave per batch row ----------------
__global__ void k_head(const float* __restrict__ hfin,
                       const float* __restrict__ fc1w, const float* __restrict__ fc1b,
                       const float* __restrict__ fc2w, const float* __restrict__ fc2b,
                       float* __restrict__ out) {
  const int tid = threadIdx.x;
  const int lane = tid & 63;
  const int wid = tid >> 6;
  const int row = blockIdx.x * 4 + wid;
  const float* h = hfin + row * HID;
  const float* w = fc1w + lane * HID;
  float acc = 0.0f;
#pragma unroll
  for (int k = 0; k < HID; k += 4) {
    const f32x4 hv = *(const f32x4*)(h + k);
    const f32x4 wv = *(const f32x4*)(w + k);
    acc += hv[0] * wv[0] + hv[1] * wv[1] + hv[2] * wv[2] + hv[3] * wv[3];
  }
  const float h1 = fmaxf(acc + fc1b[lane], 0.0f);
  float v = h1 * fc2w[lane];
#pragma unroll
  for (int off = 32; off > 0; off >>= 1) v += __shfl_down(v, off, 64);
  if (lane == 0) out[row] = sigmf(v + fc2b[0]);
}

// ---------------------------------------------------------------------------
extern "C" void kernel_launch(void* const* d_in, const int* in_sizes, int n_in,
                              void* d_out, int out_size, void* d_ws, size_t ws_size,
                              hipStream_t stream) {
  const int*   x    = (const int*)d_in[0];
  const float* emb  = (const float*)d_in[1];
  const float* w_ih = (const float*)d_in[2];
  const float* w_hh = (const float*)d_in[3];
  const float* b_ih = (const float*)d_in[4];
  const float* b_hh = (const float*)d_in[5];
  const float* fc1w = (const float*)d_in[6];
  const float* fc1b = (const float*)d_in[7];
  const float* fc2w = (const float*)d_in[8];
  const float* fc2b = (const float*)d_in[9];
  float* out = (float*)d_out;
  char* ws = (char*)d_ws;

  unsigned short* embb = (unsigned short*)(ws + 0);            // 32,000,000
  unsigned short* wihb = (unsigned short*)(ws + 32000000);     //    327,680
  unsigned short* whhp = (unsigned short*)(ws + 32327680);     //    131,072 (PERMUTED w_hh)
  float*          biasp= (float*)(ws + 32458752);              //      2,048
  float*          hfinp= (float*)(ws + 32460800);              //    524,288
  unsigned short* xgb  = (unsigned short*)(ws + 32985088);     // 209,715,200

  const long PREP_N = (long)VOCAB * (EMBP / 8) + NGATE * (EMBP / 8)
                    + NGATE * (HID / 8) + NGATE;               // 2,029,184
  k_prep<<<dim3((unsigned)((PREP_N + 255) / 256)), dim3(256), 0, stream>>>(
      emb, w_ih, w_hh, b_ih, b_hh, embb, wihb, whhp, biasp);
  k_xg_gemm<<<dim3(1600 * 4), dim3(512), 0, stream>>>(x, embb, wihb, biasp, xgb);
  k_lstm<<<dim3(BATCH / ROWS), dim3(512), 0, stream>>>(xgb, whhp, hfinp);
  k_head<<<dim3(256), dim3(256), 0, stream>>>(hfinp, fc1w, fc1b, fc2w, fc2b, out);
  (void)in_sizes; (void)n_in; (void)out_size; (void)ws_size;
}

// Round 17
// 264.008 us; speedup vs baseline: 1.1995x; 1.0023x over previous
//
#include <hip/hip_runtime.h>
#include <hip/hip_bf16.h>
#include <stdint.h>

#define VOCAB 50000
#define EMB   300
#define EMBP  320   // K padded to multiple of 64
#define HID   128
#define NGATE 512   // 4*HID
#define BATCH 1024
#define SEQ   200
#define ROWS  4     // batch rows per k_lstm block (256 blocks)
#define L2E   1.4426950408889634f

typedef __attribute__((ext_vector_type(8))) short short8;
typedef __attribute__((ext_vector_type(4))) float f32x4;

#define AS1 __attribute__((address_space(1)))
#define AS3 __attribute__((address_space(3)))

static __device__ __forceinline__ void gload_lds16(const void* g, void* s) {
  __builtin_amdgcn_global_load_lds((const AS1 uint32_t*)g, (AS3 uint32_t*)s, 16, 0, 0);
}

static __device__ __forceinline__ unsigned short f2bf(float f) {
  union { float f; unsigned u; } v; v.f = f;
  unsigned r = v.u + 0x7fffu + ((v.u >> 16) & 1u);
  return (unsigned short)(r >> 16);
}
static __device__ __forceinline__ float blo2f(unsigned u) {
  union { unsigned u; float f; } v; v.u = u << 16; return v.f;
}
static __device__ __forceinline__ float bhi2f(unsigned u) {
  union { unsigned u; float f; } v; v.u = u & 0xffff0000u; return v.f;
}
static __device__ __forceinline__ float sigmf(float x) {
  return __fdividef(1.0f, 1.0f + __expf(-x));
}
// z pre-scaled by log2(e): sigmoid(a) = 1/(1+2^-z)
static __device__ __forceinline__ float sig2(float z) {
  return __builtin_amdgcn_rcpf(1.0f + __builtin_amdgcn_exp2f(-z));
}

// ---------------- FUSED prep: all f32->bf16 conversions + bias in ONE launch
__global__ __launch_bounds__(256) void k_prep(
    const float* __restrict__ emb, const float* __restrict__ w_ih,
    const float* __restrict__ w_hh, const float* __restrict__ b_ih,
    const float* __restrict__ b_hh, unsigned short* __restrict__ embb,
    unsigned short* __restrict__ wihb, unsigned short* __restrict__ whhp,
    float* __restrict__ biasp) {
  const long EMBN = (long)VOCAB * (EMBP / 8);   // 2,000,000
  const long WIHN = NGATE * (EMBP / 8);         //    20,480
  const long WHHN = NGATE * (HID / 8);          //     8,192
  long idx = (long)blockIdx.x * blockDim.x + threadIdx.x;

  if (idx < EMBN) {
    const int row = (int)(idx / (EMBP / 8));
    const int k0 = (int)(idx - (long)row * (EMBP / 8)) * 8;
    uint4 pack;
    unsigned short* v = (unsigned short*)&pack;
#pragma unroll
    for (int j = 0; j < 8; j++) {
      const int k = k0 + j;
      v[j] = (k < EMB) ? f2bf(emb[(long)row * EMB + k]) : (unsigned short)0;
    }
    *(uint4*)(embb + (long)row * EMBP + k0) = pack;
    return;
  }
  idx -= EMBN;
  if (idx < WIHN) {
    const int row = (int)(idx / (EMBP / 8));
    const int k0 = (int)(idx - (long)row * (EMBP / 8)) * 8;
    const float s = ((row >> 7) == 2) ? (2.0f * L2E) : L2E;
    uint4 pack;
    unsigned short* v = (unsigned short*)&pack;
#pragma unroll
    for (int j = 0; j < 8; j++) {
      const int k = k0 + j;
      v[j] = (k < EMB) ? f2bf(w_ih[(long)row * EMB + k] * s) : (unsigned short)0;
    }
    const int drow = (row & 127) * 4 + (row >> 7);
    *(uint4*)(wihb + (long)drow * EMBP + k0) = pack;
    return;
  }
  idx -= WIHN;
  if (idx < WHHN) {
    const int row = (int)(idx / (HID / 8));
    const int k0 = (int)(idx - (long)row * (HID / 8)) * 8;
    const float s = ((row >> 7) == 2) ? (2.0f * L2E) : L2E;
    uint4 pack;
    unsigned short* v = (unsigned short*)&pack;
#pragma unroll
    for (int j = 0; j < 8; j++)
      v[j] = f2bf(w_hh[(long)row * HID + k0 + j] * s);
    const int drow = (row & 127) * 4 + (row >> 7);
    *(uint4*)(whhp + (long)drow * HID + k0) = pack;
    return;
  }
  idx -= WHHN;
  if (idx < NGATE) {
    const int g = (int)(idx >> 7), hid = (int)(idx & 127);
    const float s = (g == 2) ? (2.0f * L2E) : L2E;
    biasp[hid * 4 + g] = (b_ih[idx] + b_hh[idx]) * s;
  }
}

// ---------------- kernel 1: gathered GEMM  xg = emb[x] @ w_ih_perm^T + bias
// R16 math verbatim, SINGLE-buffer LDS (32KB/block): LDS occupancy limit
// rises 2 -> 5 blocks/CU, wave cap gives 4 blocks/CU (32 waves) at VGPR<=64.
// The per-step stage latency (the measured ~85% stall) is now hidden by 3
// other independent blocks instead of one half-drained partner. Barriers
// double per block but cross-block TLP fills them. K-order identical.
__global__ __launch_bounds__(512, 4) void k_xg_gemm(
    const int* __restrict__ x, const unsigned short* __restrict__ embb,
    const unsigned short* __restrict__ wihb, const float* __restrict__ biasp,
    unsigned short* __restrict__ xg) {
  __shared__ __align__(16) unsigned short Al[128 * 64];   // 16 KB
  __shared__ __align__(16) unsigned short Bl[128 * 64];   // 16 KB
  const int tid = threadIdx.x;
  const int lane = tid & 63;
  // XCD co-location: bid = q*8 + xcd ; tile_m = xcd*200 + q/4 ; tile_n = q%4
  const int bid = blockIdx.x;
  const int xcd = bid & 7;
  const int q = bid >> 3;                   // 0..799
  const int tile_m = xcd * 200 + (q >> 2);  // 0..1599
  const int tile_n = q & 3;
  const int t_idx = tile_m >> 3;            // 1024 % 128 == 0 -> tile same t
  const int b0 = (tile_m & 7) * 128;
  const int n0 = tile_n * 128;

  // staging: chunk c = tid + i*512 (i<2); row = c>>3, phys slot p = c&7
  // sigma = p ^ (row&7) ; row&7 identical for both i (64 % 8 == 0)
  const int r0 = tid >> 3;                  // 0..63
  const int sg = (tid & 7) ^ (r0 & 7);
  const unsigned short* asrc[2];
  const unsigned short* bsrc[2];
#pragma unroll
  for (int i = 0; i < 2; i++) {
    const int r = r0 + i * 64;
    const long ridx = x[(b0 + r) * SEQ + t_idx];
    asrc[i] = embb + ridx * EMBP + sg * 8;
    bsrc[i] = wihb + (long)(n0 + r) * EMBP + sg * 8;
  }

  // wave mapping: 8 waves = 4 wrow (32 M-rows) x 2 wcol (64 N-cols)
  const int wid = tid >> 6;
  const int wrow = wid >> 1, wcol = wid & 1;
  const int l15 = lane & 15, lgrp = lane >> 4;
  const int swz = (l15 & 7) << 4;

  f32x4 acc[2][4];
#pragma unroll
  for (int mt = 0; mt < 2; mt++)
#pragma unroll
    for (int nt = 0; nt < 4; nt++) acc[mt][nt] = (f32x4){0.f, 0.f, 0.f, 0.f};

#define STAGE(KS)                                                              \
  {                                                                            \
    _Pragma("unroll") for (int i = 0; i < 2; i++) {                            \
      gload_lds16(asrc[i] + (KS) * 64, (char*)Al + tid * 16 + i * 8192);       \
      gload_lds16(bsrc[i] + (KS) * 64, (char*)Bl + tid * 16 + i * 8192);       \
    }                                                                          \
  }

#define COMPUTE                                                                \
  {                                                                            \
    const char* Ar = (const char*)Al + (wrow * 32) * 128;                      \
    const char* Br = (const char*)Bl + (wcol * 64) * 128;                      \
    _Pragma("unroll") for (int kt = 0; kt < 2; kt++) {                         \
      short8 af[2], bf[4];                                                     \
      _Pragma("unroll") for (int mt = 0; mt < 2; mt++)                         \
        af[mt] = *(const short8*)(Ar + (mt * 16 + l15) * 128 + ((kt * 64 + lgrp * 16) ^ swz)); \
      _Pragma("unroll") for (int nt = 0; nt < 4; nt++)                         \
        bf[nt] = *(const short8*)(Br + (nt * 16 + l15) * 128 + ((kt * 64 + lgrp * 16) ^ swz)); \
      __builtin_amdgcn_s_setprio(1);                                           \
      _Pragma("unroll") for (int mt = 0; mt < 2; mt++)                         \
        _Pragma("unroll") for (int nt = 0; nt < 4; nt++)                       \
          acc[mt][nt] = __builtin_amdgcn_mfma_f32_16x16x32_bf16(af[mt], bf[nt], acc[mt][nt], 0, 0, 0); \
      __builtin_amdgcn_s_setprio(0);                                           \
    }                                                                          \
  }

#pragma unroll
  for (int ks = 0; ks < 5; ks++) {
    STAGE(ks);
    __syncthreads();
    COMPUTE;
    if (ks < 4) __syncthreads();   // buffer reuse fence (skip after last)
  }
#undef STAGE
#undef COMPUTE

  const int m_base = tile_m * 128 + wrow * 32;
  const int colg = n0 + wcol * 64 + l15;
  const int rsub = lgrp * 4;
  float bv[4];
#pragma unroll
  for (int nt = 0; nt < 4; nt++) bv[nt] = biasp[colg + nt * 16];
#pragma unroll
  for (int mt = 0; mt < 2; mt++)
#pragma unroll
    for (int nt = 0; nt < 4; nt++)
#pragma unroll
      for (int j = 0; j < 4; j++) {
        const long m = m_base + mt * 16 + rsub + j;
        xg[m * NGATE + colg + nt * 16] = f2bf(acc[mt][nt][j] + bv[nt]);
      }
}

// ---------------- kernel 2: sequential LSTM (R14/R16 champion, verbatim) ---
__global__ __launch_bounds__(512, 2) void k_lstm(
    const unsigned short* __restrict__ xg, const unsigned short* __restrict__ whhp,
    float* __restrict__ hfin) {
  __shared__ __align__(16) unsigned short h_lds[2 * 4 * 128];  // 2KB dbuf, XOR-swizzled
  __shared__ __align__(16) float scratch[8 * 256];             // 8KB: 1KB per wave
  const int tid = threadIdx.x;
  const int lane = tid & 63;
  const int wid = tid >> 6;        // hidden block (16 hids)
  const int b0 = blockIdx.x * ROWS;
  const int l15 = lane & 15;
  const int lgrp = lane >> 4;      // 0..3
  const int hid = wid * 16 + l15;  // updater's hid

  // A-operand: permuted w_hh rows n' = wid*64 + nt*16 + l15, k = kt*32+lgrp*8
  short8 wfr[4][4];
#pragma unroll
  for (int nt = 0; nt < 4; nt++)
#pragma unroll
    for (int kt = 0; kt < 4; kt++)
      wfr[nt][kt] = *(const short8*)(whhp + (long)(wid * 64 + nt * 16 + l15) * HID + kt * 32 + lgrp * 8);

  float c_r = 0.0f, h_r = 0.0f;    // element (row=lgrp, hid)

  ((unsigned*)h_lds)[tid] = 0;     // 512 x 4B = 2KB (both parities)
  __syncthreads();

  // B-frag (h^T): lane l15 -> batch row l15&3 (rows 4-15 dup -> garbage cols)
  const int ar = l15 & 3;
  int rdoff[4];
#pragma unroll
  for (int kt = 0; kt < 4; kt++)
    rdoff[kt] = ar * 256 + ((kt * 64 + lgrp * 16) ^ (ar << 5));
  const int hwoff = lgrp * 256 + ((2 * hid) ^ (lgrp << 5));
  const char* lb = (const char*)h_lds;

  // wave-private scratch: float addr (row r)*64 + ((hidloc*4) ^ (r*4))
  float* sw = scratch + wid * 256;
  int swr[4];                       // write: r=l15 (<4), hidloc = nt*4+lgrp
#pragma unroll
  for (int nt = 0; nt < 4; nt++)
    swr[nt] = l15 * 64 + (((nt * 4 + lgrp) * 4) ^ (l15 * 4));
  const int srd = lgrp * 64 + ((l15 * 4) ^ (lgrp * 4));  // read: r=lgrp, hidloc=l15

  // xg: elem ((t*BATCH + row)*HID + hid)*4 + gate ; this lane: row=lgrp
  const unsigned short* xbase = xg + ((long)(b0 + lgrp) * HID + hid) * 4;
  const long TSTEP = (long)BATCH * HID * 4;
  uint2 xA = *(const uint2*)xbase;
  uint2 xB = *(const uint2*)(xbase + TSTEP);
  const unsigned short* xnext = xbase + 2 * TSTEP;

#define STEP_BODY(XS, RB, WB, T)                                               \
  {                                                                            \
    const float xf0 = blo2f(XS.x), xf1 = bhi2f(XS.x);                          \
    const float xf2 = blo2f(XS.y), xf3 = bhi2f(XS.y);                          \
    if ((T) + 2 < SEQ) XS = *(const uint2*)xnext;                              \
    short8 hf[4];                                                              \
    _Pragma("unroll") for (int kt = 0; kt < 4; kt++)                           \
      hf[kt] = *(const short8*)(lb + (RB) + rdoff[kt]);                        \
    f32x4 acc[4];                                                              \
    _Pragma("unroll") for (int nt = 0; nt < 4; nt++)                           \
      acc[nt] = (f32x4){0.f, 0.f, 0.f, 0.f};                                   \
    __builtin_amdgcn_s_setprio(1);                                             \
    _Pragma("unroll") for (int kt = 0; kt < 4; kt++)                           \
      _Pragma("unroll") for (int nt = 0; nt < 4; nt++)                         \
        acc[nt] = __builtin_amdgcn_mfma_f32_16x16x32_bf16(wfr[nt][kt], hf[kt], \
                                                          acc[nt], 0, 0, 0);   \
    __builtin_amdgcn_s_setprio(0);                                             \
    if (l15 < 4) {                                                             \
      _Pragma("unroll") for (int nt = 0; nt < 4; nt++)                         \
        *(f32x4*)(sw + swr[nt]) = acc[nt];                                     \
    }                                                                          \
    __builtin_amdgcn_sched_barrier(0);                                         \
    const f32x4 g4 = *(const f32x4*)(sw + srd);                                \
    const float zi = g4[0] + xf0;                                              \
    const float zf = g4[1] + xf1;                                              \
    const float zg = g4[2] + xf2;                                              \
    const float zo = g4[3] + xf3;                                              \
    const float iv = sig2(zi);                                                 \
    const float fv = sig2(zf);                                                 \
    const float gv = 2.0f * sig2(zg) - 1.0f;                                   \
    const float ov = sig2(zo);                                                 \
    c_r = fv * c_r + iv * gv;                                                  \
    const float tc = 2.0f * sig2(c_r * (2.0f * L2E)) - 1.0f;                   \
    h_r = ov * tc;                                                             \
    *(unsigned short*)((char*)h_lds + (WB) + hwoff) = f2bf(h_r);               \
    asm volatile("s_waitcnt lgkmcnt(0)" ::: "memory");                         \
    __builtin_amdgcn_s_barrier();                                              \
    __builtin_amdgcn_sched_barrier(0);                                         \
  }

  for (int t = 0; t < SEQ; t += 2) {
    STEP_BODY(xA, 0, 1024, t);
    xnext += TSTEP;
    STEP_BODY(xB, 1024, 0, t + 1);
    xnext += TSTEP;
  }
#undef STEP_BODY

  hfin[(b0 + lgrp) * HID + hid] = h_r;
}

// ---------------- kernel 3: FC head, one wave per batch row ----------------
__global__ void k_head(const float* __restrict__ hfin,
                       const float* __restrict__ fc1w, const float* __restrict__ fc1b,
                       const float* __restrict__ fc2w, const float* __restrict__ fc2b,
                       float* __restrict__ out) {
  const int tid = threadIdx.x;
  const int lane = tid & 63;
  const int wid = tid >> 6;
  const int row = blockIdx.x * 4 + wid;
  const float* h = hfin + row * HID;
  const float* w = fc1w + lane * HID;
  float acc = 0.0f;
#pragma unroll
  for (int k = 0; k < HID; k += 4) {
    const f32x4 hv = *(const f32x4*)(h + k);
    const f32x4 wv = *(const f32x4*)(w + k);
    acc += hv[0] * wv[0] + hv[1] * wv[1] + hv[2] * wv[2] + hv[3] * wv[3];
  }
  const float h1 = fmaxf(acc + fc1b[lane], 0.0f);
  float v = h1 * fc2w[lane];
#pragma unroll
  for (int off = 32; off > 0; off >>= 1) v += __shfl_down(v, off, 64);
  if (lane == 0) out[row] = sigmf(v + fc2b[0]);
}

// ---------------------------------------------------------------------------
extern "C" void kernel_launch(void* const* d_in, const int* in_sizes, int n_in,
                              void* d_out, int out_size, void* d_ws, size_t ws_size,
                              hipStream_t stream) {
  const int*   x    = (const int*)d_in[0];
  const float* emb  = (const float*)d_in[1];
  const float* w_ih = (const float*)d_in[2];
  const float* w_hh = (const float*)d_in[3];
  const float* b_ih = (const float*)d_in[4];
  const float* b_hh = (const float*)d_in[5];
  const float* fc1w = (const float*)d_in[6];
  const float* fc1b = (const float*)d_in[7];
  const float* fc2w = (const float*)d_in[8];
  const float* fc2b = (const float*)d_in[9];
  float* out = (float*)d_out;
  char* ws = (char*)d_ws;

  unsigned short* embb = (unsigned short*)(ws + 0);            // 32,000,000
  unsigned short* wihb = (unsigned short*)(ws + 32000000);     //    327,680
  unsigned short* whhp = (unsigned short*)(ws + 32327680);     //    131,072 (PERMUTED w_hh)
  float*          biasp= (float*)(ws + 32458752);              //      2,048
  float*          hfinp= (float*)(ws + 32460800);              //    524,288
  unsigned short* xgb  = (unsigned short*)(ws + 32985088);     // 209,715,200

  const long PREP_N = (long)VOCAB * (EMBP / 8) + NGATE * (EMBP / 8)
                    + NGATE * (HID / 8) + NGATE;               // 2,029,184
  k_prep<<<dim3((unsigned)((PREP_N + 255) / 256)), dim3(256), 0, stream>>>(
      emb, w_ih, w_hh, b_ih, b_hh, embb, wihb, whhp, biasp);
  k_xg_gemm<<<dim3(1600 * 4), dim3(512), 0, stream>>>(x, embb, wihb, biasp, xgb);
  k_lstm<<<dim3(BATCH / ROWS), dim3(512), 0, stream>>>(xgb, whhp, hfinp);
  k_head<<<dim3(256), dim3(256), 0, stream>>>(hfinp, fc1w, fc1b, fc2w, fc2b, out);
  (void)in_sizes; (void)n_in; (void)out_size; (void)ws_size;
}

// Round 18
// 262.084 us; speedup vs baseline: 1.2083x; 1.0073x over previous
//
#include <hip/hip_runtime.h>
#include <hip/hip_bf16.h>
#include <stdint.h>

#define VOCAB 50000
#define EMB   300
#define EMBP  320   // K padded to multiple of 64
#define HID   128
#define NGATE 512   // 4*HID
#define BATCH 1024
#define SEQ   200
#define ROWS  4     // batch rows per k_lstm block (256 blocks)
#define L2E   1.4426950408889634f

typedef __attribute__((ext_vector_type(8))) short short8;
typedef __attribute__((ext_vector_type(4))) float f32x4;

#define AS1 __attribute__((address_space(1)))
#define AS3 __attribute__((address_space(3)))

static __device__ __forceinline__ void gload_lds16(const void* g, void* s) {
  __builtin_amdgcn_global_load_lds((const AS1 uint32_t*)g, (AS3 uint32_t*)s, 16, 0, 0);
}

static __device__ __forceinline__ unsigned short f2bf(float f) {
  union { float f; unsigned u; } v; v.f = f;
  unsigned r = v.u + 0x7fffu + ((v.u >> 16) & 1u);
  return (unsigned short)(r >> 16);
}
static __device__ __forceinline__ float blo2f(unsigned u) {
  union { unsigned u; float f; } v; v.u = u << 16; return v.f;
}
static __device__ __forceinline__ float bhi2f(unsigned u) {
  union { unsigned u; float f; } v; v.u = u & 0xffff0000u; return v.f;
}
static __device__ __forceinline__ float sigmf(float x) {
  return __fdividef(1.0f, 1.0f + __expf(-x));
}
// z pre-scaled by log2(e): sigmoid(a) = 1/(1+2^-z)
static __device__ __forceinline__ float sig2(float z) {
  return __builtin_amdgcn_rcpf(1.0f + __builtin_amdgcn_exp2f(-z));
}

// ---------------- FUSED prep: all f32->bf16 conversions + bias in ONE launch
__global__ __launch_bounds__(256) void k_prep(
    const float* __restrict__ emb, const float* __restrict__ w_ih,
    const float* __restrict__ w_hh, const float* __restrict__ b_ih,
    const float* __restrict__ b_hh, unsigned short* __restrict__ embb,
    unsigned short* __restrict__ wihb, unsigned short* __restrict__ whhp,
    float* __restrict__ biasp) {
  const long EMBN = (long)VOCAB * (EMBP / 8);   // 2,000,000
  const long WIHN = NGATE * (EMBP / 8);         //    20,480
  const long WHHN = NGATE * (HID / 8);          //     8,192
  long idx = (long)blockIdx.x * blockDim.x + threadIdx.x;

  if (idx < EMBN) {
    const int row = (int)(idx / (EMBP / 8));
    const int k0 = (int)(idx - (long)row * (EMBP / 8)) * 8;
    uint4 pack;
    unsigned short* v = (unsigned short*)&pack;
#pragma unroll
    for (int j = 0; j < 8; j++) {
      const int k = k0 + j;
      v[j] = (k < EMB) ? f2bf(emb[(long)row * EMB + k]) : (unsigned short)0;
    }
    *(uint4*)(embb + (long)row * EMBP + k0) = pack;
    return;
  }
  idx -= EMBN;
  if (idx < WIHN) {
    const int row = (int)(idx / (EMBP / 8));
    const int k0 = (int)(idx - (long)row * (EMBP / 8)) * 8;
    const float s = ((row >> 7) == 2) ? (2.0f * L2E) : L2E;
    uint4 pack;
    unsigned short* v = (unsigned short*)&pack;
#pragma unroll
    for (int j = 0; j < 8; j++) {
      const int k = k0 + j;
      v[j] = (k < EMB) ? f2bf(w_ih[(long)row * EMB + k] * s) : (unsigned short)0;
    }
    const int drow = (row & 127) * 4 + (row >> 7);
    *(uint4*)(wihb + (long)drow * EMBP + k0) = pack;
    return;
  }
  idx -= WIHN;
  if (idx < WHHN) {
    const int row = (int)(idx / (HID / 8));
    const int k0 = (int)(idx - (long)row * (HID / 8)) * 8;
    const float s = ((row >> 7) == 2) ? (2.0f * L2E) : L2E;
    uint4 pack;
    unsigned short* v = (unsigned short*)&pack;
#pragma unroll
    for (int j = 0; j < 8; j++)
      v[j] = f2bf(w_hh[(long)row * HID + k0 + j] * s);
    const int drow = (row & 127) * 4 + (row >> 7);
    *(uint4*)(whhp + (long)drow * HID + k0) = pack;
    return;
  }
  idx -= WHHN;
  if (idx < NGATE) {
    const int g = (int)(idx >> 7), hid = (int)(idx & 127);
    const float s = (g == 2) ? (2.0f * L2E) : L2E;
    biasp[hid * 4 + g] = (b_ih[idx] + b_hh[idx]) * s;
  }
}

// ---------------- kernel 1: gathered GEMM  xg = emb[x] @ w_ih_perm^T + bias
// R16 dbuf structure with T4 COUNTED-vmcnt barriers: per K-step
// {COMPUTE(buf); lgkmcnt(0); bar; STAGE(k+2,buf); vmcnt(4); bar} — the
// newest stage's 4 loads stay in flight ACROSS the barrier (vmcnt drains
// to 0 only once, at the final stage), so the L3-gather latency spans the
// compute phase instead of serializing after it. Math byte-identical.
__global__ __launch_bounds__(512, 4) void k_xg_gemm(
    const int* __restrict__ x, const unsigned short* __restrict__ embb,
    const unsigned short* __restrict__ wihb, const float* __restrict__ biasp,
    unsigned short* __restrict__ xg) {
  __shared__ __align__(16) unsigned short Al[2][128 * 64];   // 32 KB
  __shared__ __align__(16) unsigned short Bl[2][128 * 64];   // 32 KB
  const int tid = threadIdx.x;
  const int lane = tid & 63;
  // XCD co-location: bid = q*8 + xcd ; tile_m = xcd*200 + q/4 ; tile_n = q%4
  const int bid = blockIdx.x;
  const int xcd = bid & 7;
  const int q = bid >> 3;                   // 0..799
  const int tile_m = xcd * 200 + (q >> 2);  // 0..1599
  const int tile_n = q & 3;
  const int t_idx = tile_m >> 3;            // 1024 % 128 == 0 -> tile same t
  const int b0 = (tile_m & 7) * 128;
  const int n0 = tile_n * 128;

  // staging: chunk c = tid + i*512 (i<2); row = c>>3, phys slot p = c&7
  // sigma = p ^ (row&7) ; row&7 identical for both i (64 % 8 == 0)
  const int r0 = tid >> 3;                  // 0..63
  const int sg = (tid & 7) ^ (r0 & 7);
  const unsigned short* asrc[2];
  const unsigned short* bsrc[2];
#pragma unroll
  for (int i = 0; i < 2; i++) {
    const int r = r0 + i * 64;
    const long ridx = x[(b0 + r) * SEQ + t_idx];
    asrc[i] = embb + ridx * EMBP + sg * 8;
    bsrc[i] = wihb + (long)(n0 + r) * EMBP + sg * 8;
  }

  // wave mapping: 8 waves = 4 wrow (32 M-rows) x 2 wcol (64 N-cols)
  const int wid = tid >> 6;
  const int wrow = wid >> 1, wcol = wid & 1;
  const int l15 = lane & 15, lgrp = lane >> 4;
  const int swz = (l15 & 7) << 4;

  f32x4 acc[2][4];
#pragma unroll
  for (int mt = 0; mt < 2; mt++)
#pragma unroll
    for (int nt = 0; nt < 4; nt++) acc[mt][nt] = (f32x4){0.f, 0.f, 0.f, 0.f};

#define STAGE(KS, BUF)                                                         \
  {                                                                            \
    _Pragma("unroll") for (int i = 0; i < 2; i++) {                            \
      gload_lds16(asrc[i] + (KS) * 64, (char*)Al + (BUF) * 16384 + tid * 16 + i * 8192); \
      gload_lds16(bsrc[i] + (KS) * 64, (char*)Bl + (BUF) * 16384 + tid * 16 + i * 8192); \
    }                                                                          \
  }

#define COMPUTE(BUF)                                                           \
  {                                                                            \
    const char* Ar = (const char*)Al + (BUF) * 16384 + (wrow * 32) * 128;      \
    const char* Br = (const char*)Bl + (BUF) * 16384 + (wcol * 64) * 128;      \
    _Pragma("unroll") for (int kt = 0; kt < 2; kt++) {                         \
      short8 af[2], bf[4];                                                     \
      _Pragma("unroll") for (int mt = 0; mt < 2; mt++)                         \
        af[mt] = *(const short8*)(Ar + (mt * 16 + l15) * 128 + ((kt * 64 + lgrp * 16) ^ swz)); \
      _Pragma("unroll") for (int nt = 0; nt < 4; nt++)                         \
        bf[nt] = *(const short8*)(Br + (nt * 16 + l15) * 128 + ((kt * 64 + lgrp * 16) ^ swz)); \
      __builtin_amdgcn_s_setprio(1);                                           \
      _Pragma("unroll") for (int mt = 0; mt < 2; mt++)                         \
        _Pragma("unroll") for (int nt = 0; nt < 4; nt++)                       \
          acc[mt][nt] = __builtin_amdgcn_mfma_f32_16x16x32_bf16(af[mt], bf[nt], acc[mt][nt], 0, 0, 0); \
      __builtin_amdgcn_s_setprio(0);                                           \
    }                                                                          \
  }

#define WAITV4 asm volatile("s_waitcnt vmcnt(4)" ::: "memory")
#define WAITV0 asm volatile("s_waitcnt vmcnt(0)" ::: "memory")
#define WAITL  asm volatile("s_waitcnt lgkmcnt(0)" ::: "memory")
#define BAR    { __builtin_amdgcn_s_barrier(); __builtin_amdgcn_sched_barrier(0); }

  // prologue: stage both buffers; wait only for buf0 (S1 stays in flight)
  STAGE(0, 0);
  STAGE(1, 1);
  WAITV4; BAR;                       // S0 done everywhere; 4 in flight (S1)
  COMPUTE(0);                        // ks0
  WAITL; BAR;                        // all reads of buf0 done
  STAGE(2, 0); WAITV4; BAR;          // S1 done everywhere; 4 in flight (S2)
  COMPUTE(1);                        // ks1
  WAITL; BAR;
  STAGE(3, 1); WAITV4; BAR;          // S2 done; 4 in flight (S3)
  COMPUTE(0);                        // ks2
  WAITL; BAR;
  STAGE(4, 0); WAITV4; BAR;          // S3 done; 4 in flight (S4)
  COMPUTE(1);                        // ks3
  WAITL; BAR;
  WAITV0; BAR;                       // S4 done (single drain-to-0)
  COMPUTE(0);                        // ks4
#undef STAGE
#undef COMPUTE
#undef WAITV4
#undef WAITV0
#undef WAITL
#undef BAR

  const int m_base = tile_m * 128 + wrow * 32;
  const int colg = n0 + wcol * 64 + l15;
  const int rsub = lgrp * 4;
  float bv[4];
#pragma unroll
  for (int nt = 0; nt < 4; nt++) bv[nt] = biasp[colg + nt * 16];
#pragma unroll
  for (int mt = 0; mt < 2; mt++)
#pragma unroll
    for (int nt = 0; nt < 4; nt++)
#pragma unroll
      for (int j = 0; j < 4; j++) {
        const long m = m_base + mt * 16 + rsub + j;
        xg[m * NGATE + colg + nt * 16] = f2bf(acc[mt][nt][j] + bv[nt]);
      }
}

// ---------------- kernel 2: sequential LSTM (R14/R17 champion, verbatim) ---
__global__ __launch_bounds__(512, 2) void k_lstm(
    const unsigned short* __restrict__ xg, const unsigned short* __restrict__ whhp,
    float* __restrict__ hfin) {
  __shared__ __align__(16) unsigned short h_lds[2 * 4 * 128];  // 2KB dbuf, XOR-swizzled
  __shared__ __align__(16) float scratch[8 * 256];             // 8KB: 1KB per wave
  const int tid = threadIdx.x;
  const int lane = tid & 63;
  const int wid = tid >> 6;        // hidden block (16 hids)
  const int b0 = blockIdx.x * ROWS;
  const int l15 = lane & 15;
  const int lgrp = lane >> 4;      // 0..3
  const int hid = wid * 16 + l15;  // updater's hid

  // A-operand: permuted w_hh rows n' = wid*64 + nt*16 + l15, k = kt*32+lgrp*8
  short8 wfr[4][4];
#pragma unroll
  for (int nt = 0; nt < 4; nt++)
#pragma unroll
    for (int kt = 0; kt < 4; kt++)
      wfr[nt][kt] = *(const short8*)(whhp + (long)(wid * 64 + nt * 16 + l15) * HID + kt * 32 + lgrp * 8);

  float c_r = 0.0f, h_r = 0.0f;    // element (row=lgrp, hid)

  ((unsigned*)h_lds)[tid] = 0;     // 512 x 4B = 2KB (both parities)
  __syncthreads();

  // B-frag (h^T): lane l15 -> batch row l15&3 (rows 4-15 dup -> garbage cols)
  const int ar = l15 & 3;
  int rdoff[4];
#pragma unroll
  for (int kt = 0; kt < 4; kt++)
    rdoff[kt] = ar * 256 + ((kt * 64 + lgrp * 16) ^ (ar << 5));
  const int hwoff = lgrp * 256 + ((2 * hid) ^ (lgrp << 5));
  const char* lb = (const char*)h_lds;

  // wave-private scratch: float addr (row r)*64 + ((hidloc*4) ^ (r*4))
  float* sw = scratch + wid * 256;
  int swr[4];                       // write: r=l15 (<4), hidloc = nt*4+lgrp
#pragma unroll
  for (int nt = 0; nt < 4; nt++)
    swr[nt] = l15 * 64 + (((nt * 4 + lgrp) * 4) ^ (l15 * 4));
  const int srd = lgrp * 64 + ((l15 * 4) ^ (lgrp * 4));  // read: r=lgrp, hidloc=l15

  // xg: elem ((t*BATCH + row)*HID + hid)*4 + gate ; this lane: row=lgrp
  const unsigned short* xbase = xg + ((long)(b0 + lgrp) * HID + hid) * 4;
  const long TSTEP = (long)BATCH * HID * 4;
  uint2 xA = *(const uint2*)xbase;
  uint2 xB = *(const uint2*)(xbase + TSTEP);
  const unsigned short* xnext = xbase + 2 * TSTEP;

#define STEP_BODY(XS, RB, WB, T)                                               \
  {                                                                            \
    const float xf0 = blo2f(XS.x), xf1 = bhi2f(XS.x);                          \
    const float xf2 = blo2f(XS.y), xf3 = bhi2f(XS.y);                          \
    if ((T) + 2 < SEQ) XS = *(const uint2*)xnext;                              \
    short8 hf[4];                                                              \
    _Pragma("unroll") for (int kt = 0; kt < 4; kt++)                           \
      hf[kt] = *(const short8*)(lb + (RB) + rdoff[kt]);                        \
    f32x4 acc[4];                                                              \
    _Pragma("unroll") for (int nt = 0; nt < 4; nt++)                           \
      acc[nt] = (f32x4){0.f, 0.f, 0.f, 0.f};                                   \
    __builtin_amdgcn_s_setprio(1);                                             \
    _Pragma("unroll") for (int kt = 0; kt < 4; kt++)                           \
      _Pragma("unroll") for (int nt = 0; nt < 4; nt++)                         \
        acc[nt] = __builtin_amdgcn_mfma_f32_16x16x32_bf16(wfr[nt][kt], hf[kt], \
                                                          acc[nt], 0, 0, 0);   \
    __builtin_amdgcn_s_setprio(0);                                             \
    if (l15 < 4) {                                                             \
      _Pragma("unroll") for (int nt = 0; nt < 4; nt++)                         \
        *(f32x4*)(sw + swr[nt]) = acc[nt];                                     \
    }                                                                          \
    __builtin_amdgcn_sched_barrier(0);                                         \
    const f32x4 g4 = *(const f32x4*)(sw + srd);                                \
    const float zi = g4[0] + xf0;                                              \
    const float zf = g4[1] + xf1;                                              \
    const float zg = g4[2] + xf2;                                              \
    const float zo = g4[3] + xf3;                                              \
    const float iv = sig2(zi);                                                 \
    const float fv = sig2(zf);                                                 \
    const float gv = 2.0f * sig2(zg) - 1.0f;                                   \
    const float ov = sig2(zo);                                                 \
    c_r = fv * c_r + iv * gv;                                                  \
    const float tc = 2.0f * sig2(c_r * (2.0f * L2E)) - 1.0f;                   \
    h_r = ov * tc;                                                             \
    *(unsigned short*)((char*)h_lds + (WB) + hwoff) = f2bf(h_r);               \
    asm volatile("s_waitcnt lgkmcnt(0)" ::: "memory");                         \
    __builtin_amdgcn_s_barrier();                                              \
    __builtin_amdgcn_sched_barrier(0);                                         \
  }

  for (int t = 0; t < SEQ; t += 2) {
    STEP_BODY(xA, 0, 1024, t);
    xnext += TSTEP;
    STEP_BODY(xB, 1024, 0, t + 1);
    xnext += TSTEP;
  }
#undef STEP_BODY

  hfin[(b0 + lgrp) * HID + hid] = h_r;
}

// ---------------- kernel 3: FC head, one wave per batch row ----------------
__global__ void k_head(const float* __restrict__ hfin,
                       const float* __restrict__ fc1w, const float* __restrict__ fc1b,
                       const float* __restrict__ fc2w, const float* __restrict__ fc2b,
                       float* __restrict__ out) {
  const int tid = threadIdx.x;
  const int lane = tid & 63;
  const int wid = tid >> 6;
  const int row = blockIdx.x * 4 + wid;
  const float* h = hfin + row * HID;
  const float* w = fc1w + lane * HID;
  float acc = 0.0f;
#pragma unroll
  for (int k = 0; k < HID; k += 4) {
    const f32x4 hv = *(const f32x4*)(h + k);
    const f32x4 wv = *(const f32x4*)(w + k);
    acc += hv[0] * wv[0] + hv[1] * wv[1] + hv[2] * wv[2] + hv[3] * wv[3];
  }
  const float h1 = fmaxf(acc + fc1b[lane], 0.0f);
  float v = h1 * fc2w[lane];
#pragma unroll
  for (int off = 32; off > 0; off >>= 1) v += __shfl_down(v, off, 64);
  if (lane == 0) out[row] = sigmf(v + fc2b[0]);
}

// ---------------------------------------------------------------------------
extern "C" void kernel_launch(void* const* d_in, const int* in_sizes, int n_in,
                              void* d_out, int out_size, void* d_ws, size_t ws_size,
                              hipStream_t stream) {
  const int*   x    = (const int*)d_in[0];
  const float* emb  = (const float*)d_in[1];
  const float* w_ih = (const float*)d_in[2];
  const float* w_hh = (const float*)d_in[3];
  const float* b_ih = (const float*)d_in[4];
  const float* b_hh = (const float*)d_in[5];
  const float* fc1w = (const float*)d_in[6];
  const float* fc1b = (const float*)d_in[7];
  const float* fc2w = (const float*)d_in[8];
  const float* fc2b = (const float*)d_in[9];
  float* out = (float*)d_out;
  char* ws = (char*)d_ws;

  unsigned short* embb = (unsigned short*)(ws + 0);            // 32,000,000
  unsigned short* wihb = (unsigned short*)(ws + 32000000);     //    327,680
  unsigned short* whhp = (unsigned short*)(ws + 32327680);     //    131,072 (PERMUTED w_hh)
  float*          biasp= (float*)(ws + 32458752);              //      2,048
  float*          hfinp= (float*)(ws + 32460800);              //    524,288
  unsigned short* xgb  = (unsigned short*)(ws + 32985088);     // 209,715,200

  const long PREP_N = (long)VOCAB * (EMBP / 8) + NGATE * (EMBP / 8)
                    + NGATE * (HID / 8) + NGATE;               // 2,029,184
  k_prep<<<dim3((unsigned)((PREP_N + 255) / 256)), dim3(256), 0, stream>>>(
      emb, w_ih, w_hh, b_ih, b_hh, embb, wihb, whhp, biasp);
  k_xg_gemm<<<dim3(1600 * 4), dim3(512), 0, stream>>>(x, embb, wihb, biasp, xgb);
  k_lstm<<<dim3(BATCH / ROWS), dim3(512), 0, stream>>>(xgb, whhp, hfinp);
  k_head<<<dim3(256), dim3(256), 0, stream>>>(hfinp, fc1w, fc1b, fc2w, fc2b, out);
  (void)in_sizes; (void)n_in; (void)out_size; (void)ws_size;
}